// Round 1
// baseline (182.259 us; speedup 1.0000x reference)
//
#include <hip/hip_runtime.h>
#include <hip/hip_bf16.h>
#include <stdint.h>

// GATv2-style layer, MI355X. Pipeline:
//  k_convert: x,W fp32 -> bf16
//  k_gemm:    Wh = x @ W^T  (bf16 MFMA 16x16x32, direct-global frags, fp32 out)
//  k_transpose: Wh fp32 -> WhT bf16 [512][4096] (B-operand layout for PV MFMA)
//  k_svec:    s_srcT/s_dstT[h][n] = log2e * (Wh . a_src/dst)   (pre-scaled for exp2)
//  k_attn:    fused masked-softmax numer/denom + PV MFMA, j split in 2 halves
//             (no row-max: logits bounded, partials combine by addition)
//  k_stats:   h' = (num0+num1)/(l0+l1); per-column sum/sumsq via atomics
//  k_apply:   out = relu(gamma*(h'-mean)*rsqrt(var+eps)+beta)

typedef __attribute__((ext_vector_type(4))) float f32x4;
typedef __attribute__((ext_vector_type(8))) short s16x8;

#define LOG2E 1.4426950408889634f

static __device__ __forceinline__ ushort f2bf(float f) {
  union { float f; uint32_t u; } v; v.f = f;
  uint32_t r = (v.u + 0x7FFFu + ((v.u >> 16) & 1u)) >> 16;  // RNE
  return (ushort)r;
}

__global__ __launch_bounds__(256) void k_convert(const float* __restrict__ x,
                                                 const float* __restrict__ W,
                                                 ushort* __restrict__ xb,
                                                 ushort* __restrict__ wb) {
  const int idx = (blockIdx.x * 256 + threadIdx.x) * 4;
  const int NX = 4096 * 512;
  if (idx < NX) {
    float4 v = *(const float4*)(x + idx);
    ushort4 o; o.x = f2bf(v.x); o.y = f2bf(v.y); o.z = f2bf(v.z); o.w = f2bf(v.w);
    *(ushort4*)(xb + idx) = o;
  } else {
    const int k = idx - NX;
    float4 v = *(const float4*)(W + k);
    ushort4 o; o.x = f2bf(v.x); o.y = f2bf(v.y); o.z = f2bf(v.z); o.w = f2bf(v.w);
    *(ushort4*)(wb + k) = o;
  }
}

// Wh[4096][512] = x[4096][512] @ W^T ; W[512][512] row-major IS the B^T (NxK) layout.
__global__ __launch_bounds__(256) void k_gemm(const ushort* __restrict__ xb,
                                              const ushort* __restrict__ wb,
                                              float* __restrict__ Wh) {
  const int lane = threadIdx.x & 63;
  const int wv = threadIdx.x >> 6;       // 4 waves: M sub-tiles
  const int l15 = lane & 15, lg = lane >> 4;
  const int m0 = blockIdx.x * 64, n0 = blockIdx.y * 64;
  const ushort* ap = xb + (size_t)(m0 + wv * 16 + l15) * 512 + lg * 8;
  f32x4 acc[4] = {};
  for (int k0 = 0; k0 < 512; k0 += 32) {
    s16x8 a = *(const s16x8*)(ap + k0);
#pragma unroll
    for (int ct = 0; ct < 4; ++ct) {
      s16x8 b = *(const s16x8*)(wb + (size_t)(n0 + ct * 16 + l15) * 512 + k0 + lg * 8);
      acc[ct] = __builtin_amdgcn_mfma_f32_16x16x32_bf16(a, b, acc[ct], 0, 0, 0);
    }
  }
#pragma unroll
  for (int ct = 0; ct < 4; ++ct)
#pragma unroll
    for (int r = 0; r < 4; ++r)
      Wh[(size_t)(m0 + wv * 16 + lg * 4 + r) * 512 + n0 + ct * 16 + l15] = acc[ct][r];
}

__global__ __launch_bounds__(256) void k_transpose(const float* __restrict__ Wh,
                                                   ushort* __restrict__ WhT) {
  __shared__ float tile[32][33];
  const int t = threadIdx.x;
  const int r0 = blockIdx.x * 32, c0 = blockIdx.y * 32;
  const int tc = t & 31, tr = t >> 5;  // tr 0..7
#pragma unroll
  for (int p = 0; p < 4; ++p)
    tile[tr + p * 8][tc] = Wh[(size_t)(r0 + tr + p * 8) * 512 + c0 + tc];
  __syncthreads();
#pragma unroll
  for (int p = 0; p < 4; ++p)
    WhT[(size_t)(c0 + tr + p * 8) * 4096 + r0 + tc] = f2bf(tile[tc][tr + p * 8]);
}

__global__ __launch_bounds__(256) void k_svec(const float* __restrict__ Wh,
                                              const float* __restrict__ a,
                                              float* __restrict__ ssrcT,
                                              float* __restrict__ sdstT) {
  const int t = threadIdx.x;
  const int j = blockIdx.x * 32 + (t >> 3);
  const int h = t & 7;
  const float* row = Wh + (size_t)j * 512 + h * 64;
  float s1 = 0.f, s2 = 0.f;
#pragma unroll
  for (int d = 0; d < 64; d += 4) {
    float4 w4 = *(const float4*)(row + d);
    float4 as = *(const float4*)(a + d);
    float4 ad = *(const float4*)(a + 64 + d);
    s1 += w4.x * as.x + w4.y * as.y + w4.z * as.z + w4.w * as.w;
    s2 += w4.x * ad.x + w4.y * ad.y + w4.z * ad.z + w4.w * ad.w;
  }
  ssrcT[h * 4096 + j] = s1 * LOG2E;  // a_src pairs with s_src (j index)
  sdstT[h * 4096 + j] = s2 * LOG2E;  // a_dst pairs with s_dst (i index)
}

__global__ void k_zero(float* p, int n) {
  int i = blockIdx.x * 256 + threadIdx.x;
  if (i < n) p[i] = 0.f;
}

// grid (128 i-blocks, 2 j-halves), 512 threads = 8 waves = 8 heads.
// Each wave: 32 rows (2 row-tiles) x its head's 64 cols (4 col-tiles).
__global__ __launch_bounds__(512) void k_attn(const int* __restrict__ adj,
                                              const ushort* __restrict__ WhT,
                                              const float* __restrict__ ssrcT,
                                              const float* __restrict__ sdstT,
                                              float* __restrict__ num,
                                              float* __restrict__ lbuf) {
  const int lane = threadIdx.x & 63;
  const int h = threadIdx.x >> 6;  // wave == head
  const int l15 = lane & 15, lg = lane >> 4;
  const int i0 = blockIdx.x * 32;
  const int jh = blockIdx.y;
  const int jbase = jh * 2048;
  const float sd0 = sdstT[h * 4096 + i0 + l15];
  const float sd1 = sdstT[h * 4096 + i0 + 16 + l15];
  f32x4 acc[2][4] = {};
  float lacc0 = 0.f, lacc1 = 0.f;
  const int* adjr0 = adj + (size_t)(i0 + l15) * 4096;
  const int* adjr1 = adj + (size_t)(i0 + 16 + l15) * 4096;
  const float* ssp = ssrcT + h * 4096;
  const ushort* bbase = WhT + (size_t)(h * 64 + l15) * 4096 + jbase + lg * 8;

  for (int jb = 0; jb < 2048; jb += 32) {
    const int j0 = jbase + jb + lg * 8;  // this lane's 8 consecutive j (A-frag k)
    float4 u = *(const float4*)(ssp + j0);
    float4 v = *(const float4*)(ssp + j0 + 4);
    float ss[8] = {u.x, u.y, u.z, u.w, v.x, v.y, v.z, v.w};
    int4 a0 = *(const int4*)(adjr0 + j0);
    int4 a0b = *(const int4*)(adjr0 + j0 + 4);
    int4 a1 = *(const int4*)(adjr1 + j0);
    int4 a1b = *(const int4*)(adjr1 + j0 + 4);
    int am0[8] = {a0.x, a0.y, a0.z, a0.w, a0b.x, a0b.y, a0b.z, a0b.w};
    int am1[8] = {a1.x, a1.y, a1.z, a1.w, a1b.x, a1b.y, a1b.z, a1b.w};
    s16x8 pa0, pa1;
#pragma unroll
    for (int q = 0; q < 8; ++q) {
      float e0 = sd0 + ss[q];
      e0 = fmaxf(e0, 0.2f * e0);                       // leaky_relu (log2-scaled)
      float w0 = am0[q] ? __builtin_amdgcn_exp2f(e0) : 0.f;
      lacc0 += w0;
      pa0[q] = (short)f2bf(w0);
      float e1 = sd1 + ss[q];
      e1 = fmaxf(e1, 0.2f * e1);
      float w1 = am1[q] ? __builtin_amdgcn_exp2f(e1) : 0.f;
      lacc1 += w1;
      pa1[q] = (short)f2bf(w1);
    }
    const ushort* bp = bbase + jb;
#pragma unroll
    for (int ct = 0; ct < 4; ++ct) {
      s16x8 b = *(const s16x8*)(bp + (size_t)ct * 16 * 4096);
      acc[0][ct] = __builtin_amdgcn_mfma_f32_16x16x32_bf16(pa0, b, acc[0][ct], 0, 0, 0);
      acc[1][ct] = __builtin_amdgcn_mfma_f32_16x16x32_bf16(pa1, b, acc[1][ct], 0, 0, 0);
    }
  }
  // softmax denominator: reduce partial sums across the 4 lane-groups
  lacc0 += __shfl_xor(lacc0, 16); lacc0 += __shfl_xor(lacc0, 32);
  lacc1 += __shfl_xor(lacc1, 16); lacc1 += __shfl_xor(lacc1, 32);
  if (lane < 16) {
    lbuf[(size_t)(jh * 8 + h) * 4096 + i0 + lane] = lacc0;
    lbuf[(size_t)(jh * 8 + h) * 4096 + i0 + 16 + lane] = lacc1;
  }
#pragma unroll
  for (int rt = 0; rt < 2; ++rt)
#pragma unroll
    for (int ct = 0; ct < 4; ++ct)
#pragma unroll
      for (int r = 0; r < 4; ++r)
        num[((size_t)jh * 4096 + i0 + rt * 16 + lg * 4 + r) * 512 + h * 64 + ct * 16 + l15] =
            acc[rt][ct][r];
}

__global__ __launch_bounds__(256) void k_stats(const float* __restrict__ num,
                                               const float* __restrict__ lbuf,
                                               float* __restrict__ hp,
                                               float* __restrict__ stats) {
  const int t = threadIdx.x;
  const int r0 = blockIdx.x * 16;
  float s1a = 0.f, s2a = 0.f, s1b = 0.f, s2b = 0.f;
  for (int r = r0; r < r0 + 16; ++r) {
#pragma unroll
    for (int q = 0; q < 2; ++q) {
      const int c = t + q * 256;
      const int hh = c >> 6;
      float l = lbuf[hh * 4096 + r] + lbuf[(8 + hh) * 4096 + r];
      float v = (num[(size_t)r * 512 + c] + num[((size_t)4096 + r) * 512 + c]) / l;
      hp[(size_t)r * 512 + c] = v;
      if (q == 0) { s1a += v; s2a += v * v; } else { s1b += v; s2b += v * v; }
    }
  }
  atomicAdd(&stats[t], s1a);
  atomicAdd(&stats[t + 256], s1b);
  atomicAdd(&stats[512 + t], s2a);
  atomicAdd(&stats[512 + t + 256], s2b);
}

__global__ __launch_bounds__(256) void k_apply(const float* __restrict__ hp,
                                               const float* __restrict__ stats,
                                               const float* __restrict__ gamma,
                                               const float* __restrict__ beta,
                                               float* __restrict__ out) {
  const int idx = (blockIdx.x * 256 + threadIdx.x) * 4;
  const int c0 = idx & 511;
  float4 v = *(const float4*)(hp + idx);
  float vv[4] = {v.x, v.y, v.z, v.w};
  float o[4];
#pragma unroll
  for (int q = 0; q < 4; ++q) {
    const int c = c0 + q;
    float mean = stats[c] * (1.f / 4096.f);
    float var = stats[512 + c] * (1.f / 4096.f) - mean * mean;
    float val = (vv[q] - mean) * rsqrtf(var + 1e-5f) * gamma[c] + beta[c];
    o[q] = fmaxf(val, 0.f);
  }
  *(float4*)(out + idx) = make_float4(o[0], o[1], o[2], o[3]);
}

extern "C" void kernel_launch(void* const* d_in, const int* in_sizes, int n_in,
                              void* d_out, int out_size, void* d_ws, size_t ws_size,
                              hipStream_t stream) {
  const float* x = (const float*)d_in[0];
  const int* adj = (const int*)d_in[1];
  const float* W = (const float*)d_in[2];
  const float* a = (const float*)d_in[3];
  const float* gamma = (const float*)d_in[4];
  const float* beta = (const float*)d_in[5];
  float* out = (float*)d_out;

  char* ws = (char*)d_ws;
  size_t off = 0;
  auto alloc = [&](size_t bytes) -> void* {
    void* p = ws + off;
    off += (bytes + 255) & ~(size_t)255;
    return p;
  };
  ushort* xb   = (ushort*)alloc((size_t)4096 * 512 * 2);
  ushort* wb   = (ushort*)alloc((size_t)512 * 512 * 2);
  float*  Wh   = (float*)alloc((size_t)4096 * 512 * 4);
  ushort* WhT  = (ushort*)alloc((size_t)512 * 4096 * 2);
  float*  ssrcT = (float*)alloc((size_t)8 * 4096 * 4);
  float*  sdstT = (float*)alloc((size_t)8 * 4096 * 4);
  float*  num  = (float*)alloc((size_t)2 * 4096 * 512 * 4);
  float*  lbuf = (float*)alloc((size_t)16 * 4096 * 4);
  float*  hp   = (float*)alloc((size_t)4096 * 512 * 4);
  float*  stats = (float*)alloc((size_t)1024 * 4);
  // total ~41 MB of d_ws

  hipLaunchKernelGGL(k_convert, dim3(2304), dim3(256), 0, stream, x, W, xb, wb);
  hipLaunchKernelGGL(k_gemm, dim3(64, 8), dim3(256), 0, stream, xb, wb, Wh);
  hipLaunchKernelGGL(k_transpose, dim3(128, 16), dim3(256), 0, stream, Wh, WhT);
  hipLaunchKernelGGL(k_svec, dim3(128), dim3(256), 0, stream, Wh, a, ssrcT, sdstT);
  hipLaunchKernelGGL(k_zero, dim3(4), dim3(256), 0, stream, stats, 1024);
  hipLaunchKernelGGL(k_attn, dim3(128, 2), dim3(512), 0, stream, adj, WhT, ssrcT, sdstT, num, lbuf);
  hipLaunchKernelGGL(k_stats, dim3(256), dim3(256), 0, stream, num, lbuf, hp, stats);
  hipLaunchKernelGGL(k_apply, dim3(2048), dim3(256), 0, stream, hp, stats, gamma, beta, out);
}

// Round 2
// 172.455 us; speedup vs baseline: 1.0569x; 1.0569x over previous
//
#include <hip/hip_runtime.h>
#include <hip/hip_bf16.h>
#include <stdint.h>

// GATv2-style layer, MI355X. Pipeline:
//  k_convert: x,W fp32 -> bf16
//  k_pack:    adj int32 -> 1-bit mask (4096x4096 bits = 2 MB, __ballot)
//  k_gemm:    Wh = x @ W^T  (bf16 MFMA 16x16x32, fp32 out)
//  k_transpose: Wh fp32 -> WhT bf16 [512][4096] (B-operand layout for PV MFMA)
//  k_svec:    s_srcT/s_dstT[h][n] = log2e * (Wh . a_src/dst)   (pre-scaled for exp2)
//  k_attn:    fused masked-softmax numer/denom + PV MFMA, j split in 4 slices
//             (no row-max: logits bounded, partials combine by addition);
//             register double-buffered loads; num stored bf16
//  k_stats:   h' = (sum num)/(sum l); per-column sum/sumsq via atomics
//  k_apply:   out = relu(gamma*(h'-mean)*rsqrt(var+eps)+beta)

typedef __attribute__((ext_vector_type(4))) float f32x4;
typedef __attribute__((ext_vector_type(8))) short s16x8;

#define LOG2E 1.4426950408889634f

static __device__ __forceinline__ ushort f2bf(float f) {
  union { float f; uint32_t u; } v; v.f = f;
  uint32_t r = (v.u + 0x7FFFu + ((v.u >> 16) & 1u)) >> 16;  // RNE
  return (ushort)r;
}

static __device__ __forceinline__ short bf16b(float f) {
  __hip_bfloat16 h = __float2bfloat16(f);
  union { __hip_bfloat16 h; short s; } c; c.h = h;
  return c.s;
}

static __device__ __forceinline__ float bf2f(ushort u) {
  union { uint32_t u; float f; } c; c.u = ((uint32_t)u) << 16;
  return c.f;
}

__global__ __launch_bounds__(256) void k_convert(const float* __restrict__ x,
                                                 const float* __restrict__ W,
                                                 ushort* __restrict__ xb,
                                                 ushort* __restrict__ wb) {
  const int idx = (blockIdx.x * 256 + threadIdx.x) * 4;
  const int NX = 4096 * 512;
  if (idx < NX) {
    float4 v = *(const float4*)(x + idx);
    ushort4 o; o.x = f2bf(v.x); o.y = f2bf(v.y); o.z = f2bf(v.z); o.w = f2bf(v.w);
    *(ushort4*)(xb + idx) = o;
  } else {
    const int k = idx - NX;
    float4 v = *(const float4*)(W + k);
    ushort4 o; o.x = f2bf(v.x); o.y = f2bf(v.y); o.z = f2bf(v.z); o.w = f2bf(v.w);
    *(ushort4*)(wb + k) = o;
  }
}

// adj[4096][4096] int32 -> maskw[4096][64] uint64 (bit j&63 of word j>>6)
__global__ __launch_bounds__(256) void k_pack(const int* __restrict__ adj,
                                              unsigned long long* __restrict__ maskw) {
  const size_t elem = (size_t)blockIdx.x * 256 + threadIdx.x;
  const int lane = threadIdx.x & 63;
  const int v = adj[elem];
  unsigned long long b = __ballot(v > 0);
  if (lane == 0) maskw[elem >> 6] = b;
}

// Wh[4096][512] = x[4096][512] @ W^T ; W[512][512] row-major IS the B^T (NxK) layout.
__global__ __launch_bounds__(256) void k_gemm(const ushort* __restrict__ xb,
                                              const ushort* __restrict__ wb,
                                              float* __restrict__ Wh) {
  const int lane = threadIdx.x & 63;
  const int wv = threadIdx.x >> 6;       // 4 waves: M sub-tiles
  const int l15 = lane & 15, lg = lane >> 4;
  const int m0 = blockIdx.x * 64, n0 = blockIdx.y * 64;
  const ushort* ap = xb + (size_t)(m0 + wv * 16 + l15) * 512 + lg * 8;
  f32x4 acc[4] = {};
  for (int k0 = 0; k0 < 512; k0 += 32) {
    s16x8 a = *(const s16x8*)(ap + k0);
#pragma unroll
    for (int ct = 0; ct < 4; ++ct) {
      s16x8 b = *(const s16x8*)(wb + (size_t)(n0 + ct * 16 + l15) * 512 + k0 + lg * 8);
      acc[ct] = __builtin_amdgcn_mfma_f32_16x16x32_bf16(a, b, acc[ct], 0, 0, 0);
    }
  }
#pragma unroll
  for (int ct = 0; ct < 4; ++ct)
#pragma unroll
    for (int r = 0; r < 4; ++r)
      Wh[(size_t)(m0 + wv * 16 + lg * 4 + r) * 512 + n0 + ct * 16 + l15] = acc[ct][r];
}

__global__ __launch_bounds__(256) void k_transpose(const float* __restrict__ Wh,
                                                   ushort* __restrict__ WhT) {
  __shared__ float tile[32][33];
  const int t = threadIdx.x;
  const int r0 = blockIdx.x * 32, c0 = blockIdx.y * 32;
  const int tc = t & 31, tr = t >> 5;  // tr 0..7
#pragma unroll
  for (int p = 0; p < 4; ++p)
    tile[tr + p * 8][tc] = Wh[(size_t)(r0 + tr + p * 8) * 512 + c0 + tc];
  __syncthreads();
#pragma unroll
  for (int p = 0; p < 4; ++p)
    WhT[(size_t)(c0 + tr + p * 8) * 4096 + r0 + tc] = f2bf(tile[tc][tr + p * 8]);
}

__global__ __launch_bounds__(256) void k_svec(const float* __restrict__ Wh,
                                              const float* __restrict__ a,
                                              float* __restrict__ ssrcT,
                                              float* __restrict__ sdstT) {
  const int t = threadIdx.x;
  const int j = blockIdx.x * 32 + (t >> 3);
  const int h = t & 7;
  const float* row = Wh + (size_t)j * 512 + h * 64;
  float s1 = 0.f, s2 = 0.f;
#pragma unroll
  for (int d = 0; d < 64; d += 4) {
    float4 w4 = *(const float4*)(row + d);
    float4 as = *(const float4*)(a + d);
    float4 ad = *(const float4*)(a + 64 + d);
    s1 += w4.x * as.x + w4.y * as.y + w4.z * as.z + w4.w * as.w;
    s2 += w4.x * ad.x + w4.y * ad.y + w4.z * ad.z + w4.w * ad.w;
  }
  ssrcT[h * 4096 + j] = s1 * LOG2E;  // a_src pairs with s_src (j index)
  sdstT[h * 4096 + j] = s2 * LOG2E;  // a_dst pairs with s_dst (i index)
}

__global__ void k_zero(float* p, int n) {
  int i = blockIdx.x * 256 + threadIdx.x;
  if (i < n) p[i] = 0.f;
}

// grid (128 i-blocks, 4 j-slices), 512 threads = 8 waves = 8 heads.
// Each wave: 32 rows (2 row-tiles) x its head's 64 cols (4 col-tiles), 1024 j.
// Register double-buffered in 32-j half-chunks; mask word shared per 64-j chunk.
__global__ __launch_bounds__(512, 4) void k_attn(
    const unsigned long long* __restrict__ maskw,
    const ushort* __restrict__ WhT,
    const float* __restrict__ ssrcT,
    const float* __restrict__ sdstT,
    ushort* __restrict__ num,     // [4][4096][512] bf16
    float* __restrict__ lbuf) {   // [4][8][4096]
  const int lane = threadIdx.x & 63;
  const int h = threadIdx.x >> 6;  // wave == head
  const int l15 = lane & 15, lg = lane >> 4;
  const int i0 = blockIdx.x * 32;
  const int jh = blockIdx.y;
  const int jbase = jh * 1024;

  const float sd0 = sdstT[h * 4096 + i0 + l15];
  const float sd1 = sdstT[h * 4096 + i0 + 16 + l15];
  const float* ssp = ssrcT + h * 4096 + jbase + lg * 8;
  const ushort* bp = WhT + (size_t)(h * 64 + l15) * 4096 + jbase + lg * 8;
  const unsigned long long* mr0 = maskw + (size_t)(i0 + l15) * 64 + (jbase >> 6);
  const unsigned long long* mr1 = maskw + (size_t)(i0 + 16 + l15) * 64 + (jbase >> 6);

  f32x4 acc[2][4] = {};
  float lacc0 = 0.f, lacc1 = 0.f;

  s16x8 bA[4], bB[4];
  float4 uA, vA, uB, vB;
  unsigned long long mC0, mC1, mN0, mN1;
  const int shA = lg * 8, shB = 32 + lg * 8;

#define LOADF(bX, uX, vX, c)                                                  \
  {                                                                           \
    uX = *(const float4*)(ssp + (c));                                         \
    vX = *(const float4*)(ssp + (c) + 4);                                     \
    _Pragma("unroll")                                                         \
    for (int ct = 0; ct < 4; ++ct)                                            \
      bX[ct] = *(const s16x8*)(bp + (c) + (size_t)ct * 16 * 4096);            \
  }

#define COMP(bX, uX, vX, sh)                                                  \
  {                                                                           \
    float s8[8] = {uX.x, uX.y, uX.z, uX.w, vX.x, vX.y, vX.z, vX.w};           \
    uint32_t mm0 = (uint32_t)(mC0 >> (sh));                                   \
    uint32_t mm1 = (uint32_t)(mC1 >> (sh));                                   \
    s16x8 pa0, pa1;                                                           \
    _Pragma("unroll")                                                         \
    for (int q = 0; q < 8; ++q) {                                             \
      float e0 = sd0 + s8[q]; e0 = fmaxf(e0, 0.2f * e0);                      \
      float x0 = __builtin_amdgcn_exp2f(e0);                                  \
      float w0 = ((mm0 >> q) & 1) ? x0 : 0.f;                                 \
      lacc0 += w0; pa0[q] = bf16b(w0);                                        \
      float e1 = sd1 + s8[q]; e1 = fmaxf(e1, 0.2f * e1);                      \
      float x1 = __builtin_amdgcn_exp2f(e1);                                  \
      float w1 = ((mm1 >> q) & 1) ? x1 : 0.f;                                 \
      lacc1 += w1; pa1[q] = bf16b(w1);                                        \
    }                                                                         \
    _Pragma("unroll")                                                         \
    for (int ct = 0; ct < 4; ++ct) {                                          \
      acc[0][ct] = __builtin_amdgcn_mfma_f32_16x16x32_bf16(pa0, bX[ct], acc[0][ct], 0, 0, 0); \
      acc[1][ct] = __builtin_amdgcn_mfma_f32_16x16x32_bf16(pa1, bX[ct], acc[1][ct], 0, 0, 0); \
    }                                                                         \
  }

  mN0 = mr0[0]; mN1 = mr1[0];
  mC0 = mN0; mC1 = mN1;
  LOADF(bA, uA, vA, 0);
  for (int jb = 0; jb < 960; jb += 64) {
    LOADF(bB, uB, vB, jb + 32);
    mN0 = mr0[(jb + 64) >> 6]; mN1 = mr1[(jb + 64) >> 6];
    COMP(bA, uA, vA, shA);
    LOADF(bA, uA, vA, jb + 64);
    COMP(bB, uB, vB, shB);
    mC0 = mN0; mC1 = mN1;
  }
  LOADF(bB, uB, vB, 992);
  COMP(bA, uA, vA, shA);
  COMP(bB, uB, vB, shB);
#undef LOADF
#undef COMP

  // softmax denominator: reduce partial sums across the 4 lane-groups
  lacc0 += __shfl_xor(lacc0, 16); lacc0 += __shfl_xor(lacc0, 32);
  lacc1 += __shfl_xor(lacc1, 16); lacc1 += __shfl_xor(lacc1, 32);
  if (lane < 16) {
    lbuf[((size_t)jh * 8 + h) * 4096 + i0 + lane] = lacc0;
    lbuf[((size_t)jh * 8 + h) * 4096 + i0 + 16 + lane] = lacc1;
  }
  ushort* np = num + (size_t)jh * 4096 * 512;
#pragma unroll
  for (int rt = 0; rt < 2; ++rt)
#pragma unroll
    for (int ct = 0; ct < 4; ++ct)
#pragma unroll
      for (int r = 0; r < 4; ++r)
        np[(size_t)(i0 + rt * 16 + lg * 4 + r) * 512 + h * 64 + ct * 16 + l15] =
            (ushort)bf16b(acc[rt][ct][r]);
}

__global__ __launch_bounds__(256) void k_stats(const ushort* __restrict__ num,
                                               const float* __restrict__ lbuf,
                                               float* __restrict__ hp,
                                               float* __restrict__ stats) {
  const int t = threadIdx.x;
  const int r0 = blockIdx.x * 16;
  float s1a = 0.f, s2a = 0.f, s1b = 0.f, s2b = 0.f;
  for (int r = r0; r < r0 + 16; ++r) {
#pragma unroll
    for (int q = 0; q < 2; ++q) {
      const int c = t + q * 256;
      const int hh = c >> 6;
      float l = lbuf[hh * 4096 + r] + lbuf[(8 + hh) * 4096 + r] +
                lbuf[(16 + hh) * 4096 + r] + lbuf[(24 + hh) * 4096 + r];
      float rl = __builtin_amdgcn_rcpf(l);
      float nsum = bf2f(num[(size_t)r * 512 + c]) +
                   bf2f(num[(size_t)(4096 + r) * 512 + c]) +
                   bf2f(num[(size_t)(8192 + r) * 512 + c]) +
                   bf2f(num[(size_t)(12288 + r) * 512 + c]);
      float v = nsum * rl;
      hp[(size_t)r * 512 + c] = v;
      if (q == 0) { s1a += v; s2a += v * v; } else { s1b += v; s2b += v * v; }
    }
  }
  atomicAdd(&stats[t], s1a);
  atomicAdd(&stats[t + 256], s1b);
  atomicAdd(&stats[512 + t], s2a);
  atomicAdd(&stats[512 + t + 256], s2b);
}

__global__ __launch_bounds__(256) void k_apply(const float* __restrict__ hp,
                                               const float* __restrict__ stats,
                                               const float* __restrict__ gamma,
                                               const float* __restrict__ beta,
                                               float* __restrict__ out) {
  const int idx = (blockIdx.x * 256 + threadIdx.x) * 4;
  const int c0 = idx & 511;
  float4 v = *(const float4*)(hp + idx);
  float vv[4] = {v.x, v.y, v.z, v.w};
  float o[4];
#pragma unroll
  for (int q = 0; q < 4; ++q) {
    const int c = c0 + q;
    float mean = stats[c] * (1.f / 4096.f);
    float var = stats[512 + c] * (1.f / 4096.f) - mean * mean;
    float val = (vv[q] - mean) * rsqrtf(var + 1e-5f) * gamma[c] + beta[c];
    o[q] = fmaxf(val, 0.f);
  }
  *(float4*)(out + idx) = make_float4(o[0], o[1], o[2], o[3]);
}

extern "C" void kernel_launch(void* const* d_in, const int* in_sizes, int n_in,
                              void* d_out, int out_size, void* d_ws, size_t ws_size,
                              hipStream_t stream) {
  const float* x = (const float*)d_in[0];
  const int* adj = (const int*)d_in[1];
  const float* W = (const float*)d_in[2];
  const float* a = (const float*)d_in[3];
  const float* gamma = (const float*)d_in[4];
  const float* beta = (const float*)d_in[5];
  float* out = (float*)d_out;

  char* ws = (char*)d_ws;
  size_t off = 0;
  auto alloc = [&](size_t bytes) -> void* {
    void* p = ws + off;
    off += (bytes + 255) & ~(size_t)255;
    return p;
  };
  ushort* xb    = (ushort*)alloc((size_t)4096 * 512 * 2);
  ushort* wb    = (ushort*)alloc((size_t)512 * 512 * 2);
  float*  Wh    = (float*)alloc((size_t)4096 * 512 * 4);
  ushort* WhT   = (ushort*)alloc((size_t)512 * 4096 * 2);
  float*  ssrcT = (float*)alloc((size_t)8 * 4096 * 4);
  float*  sdstT = (float*)alloc((size_t)8 * 4096 * 4);
  ushort* num   = (ushort*)alloc((size_t)4 * 4096 * 512 * 2);   // bf16 partial numerators
  float*  lbuf  = (float*)alloc((size_t)32 * 4096 * 4);
  float*  hp    = (float*)alloc((size_t)4096 * 512 * 4);
  float*  stats = (float*)alloc((size_t)1024 * 4);
  unsigned long long* maskw = (unsigned long long*)alloc((size_t)4096 * 64 * 8);
  // total ~43.3 MB of d_ws

  hipLaunchKernelGGL(k_convert, dim3(2304), dim3(256), 0, stream, x, W, xb, wb);
  hipLaunchKernelGGL(k_pack, dim3(65536), dim3(256), 0, stream, adj, maskw);
  hipLaunchKernelGGL(k_gemm, dim3(64, 8), dim3(256), 0, stream, xb, wb, Wh);
  hipLaunchKernelGGL(k_transpose, dim3(128, 16), dim3(256), 0, stream, Wh, WhT);
  hipLaunchKernelGGL(k_svec, dim3(128), dim3(256), 0, stream, Wh, a, ssrcT, sdstT);
  hipLaunchKernelGGL(k_zero, dim3(4), dim3(256), 0, stream, stats, 1024);
  hipLaunchKernelGGL(k_attn, dim3(128, 4), dim3(512), 0, stream, maskw, WhT, ssrcT, sdstT, num, lbuf);
  hipLaunchKernelGGL(k_stats, dim3(256), dim3(256), 0, stream, num, lbuf, hp, stats);
  hipLaunchKernelGGL(k_apply, dim3(2048), dim3(256), 0, stream, hp, stats, gamma, beta, out);
}

// Round 3
// 162.313 us; speedup vs baseline: 1.1229x; 1.0625x over previous
//
#include <hip/hip_runtime.h>
#include <hip/hip_bf16.h>
#include <stdint.h>

// GATv2-style layer, MI355X. 6 kernels:
//  k_convert: x,W fp32 -> bf16
//  k_pack:    adj int32 -> bitmask (2 MB) + zero stats
//  k_gemm:    Wh = x @ W^T (bf16 MFMA) -> WhT bf16 (LDS transpose) + s_src/s_dst
//             (svec via shfl reduction from acc frags; no fp32 Wh buffer)
//  k_attn:    fused masked-softmax numer/denom + PV MFMA, 8 j-slices
//             (no row-max: logits bounded; partials combine by addition)
//  k_stats:   column sums of h' = (sum num)/(sum l) via atomics; writes linv
//  k_apply:   recompute h', apply layernorm + relu
// num (33.5 MB, bf16) aliases xb/wb which are dead after k_gemm.

typedef __attribute__((ext_vector_type(4))) float f32x4;
typedef __attribute__((ext_vector_type(8))) short s16x8;

#define LOG2E 1.4426950408889634f

static __device__ __forceinline__ ushort f2bf(float f) {
  union { float f; uint32_t u; } v; v.f = f;
  uint32_t r = (v.u + 0x7FFFu + ((v.u >> 16) & 1u)) >> 16;  // RNE
  return (ushort)r;
}

static __device__ __forceinline__ short bf16b(float f) {
  __hip_bfloat16 h = __float2bfloat16(f);
  union { __hip_bfloat16 h; short s; } c; c.h = h;
  return c.s;
}

static __device__ __forceinline__ float bf2f(ushort u) {
  union { uint32_t u; float f; } c; c.u = ((uint32_t)u) << 16;
  return c.f;
}

__global__ __launch_bounds__(256) void k_convert(const float* __restrict__ x,
                                                 const float* __restrict__ W,
                                                 ushort* __restrict__ xb,
                                                 ushort* __restrict__ wb) {
  const int idx = (blockIdx.x * 256 + threadIdx.x) * 4;
  const int NX = 4096 * 512;
  if (idx < NX) {
    float4 v = *(const float4*)(x + idx);
    ushort4 o; o.x = f2bf(v.x); o.y = f2bf(v.y); o.z = f2bf(v.z); o.w = f2bf(v.w);
    *(ushort4*)(xb + idx) = o;
  } else {
    const int k = idx - NX;
    float4 v = *(const float4*)(W + k);
    ushort4 o; o.x = f2bf(v.x); o.y = f2bf(v.y); o.z = f2bf(v.z); o.w = f2bf(v.w);
    *(ushort4*)(wb + k) = o;
  }
}

// adj[4096][4096] int32 -> maskw[4096*64] u64 (bit j&63 of word j>>6); zero stats.
__global__ __launch_bounds__(256) void k_pack(const int* __restrict__ adj,
                                              unsigned long long* __restrict__ maskw,
                                              float* __restrict__ stats) {
  const int t = threadIdx.x;
  if (blockIdx.x == 0) {
    stats[t] = 0.f; stats[t + 256] = 0.f; stats[t + 512] = 0.f; stats[t + 768] = 0.f;
  }
  const size_t base = (size_t)blockIdx.x * 8192;
  const int lane = t & 63;
#pragma unroll 4
  for (int it = 0; it < 32; ++it) {
    const size_t elem = base + it * 256 + t;
    unsigned long long b = __ballot(adj[elem] > 0);
    if (lane == 0) maskw[elem >> 6] = b;
  }
}

// Per block: 64 rows (m0) x one head's 64 cols. K=512 direct-global MFMA.
// Epilogue: s_src/s_dst via shfl_xor reduce; WhT bf16 via LDS transpose.
__global__ __launch_bounds__(256) void k_gemm(const ushort* __restrict__ xb,
                                              const ushort* __restrict__ wb,
                                              const float* __restrict__ a,
                                              ushort* __restrict__ WhT,
                                              float* __restrict__ ssrcT,
                                              float* __restrict__ sdstT) {
  __shared__ float tl[64 * 65];
  const int lane = threadIdx.x & 63;
  const int wv = threadIdx.x >> 6;       // 4 waves: M sub-tiles
  const int l15 = lane & 15, lg = lane >> 4;
  const int m0 = blockIdx.x * 64;
  const int h = blockIdx.y;
  const int n0 = h * 64;
  const ushort* ap = xb + (size_t)(m0 + wv * 16 + l15) * 512 + lg * 8;
  f32x4 acc[4] = {};
  for (int k0 = 0; k0 < 512; k0 += 32) {
    s16x8 av = *(const s16x8*)(ap + k0);
#pragma unroll
    for (int ct = 0; ct < 4; ++ct) {
      s16x8 b = *(const s16x8*)(wb + (size_t)(n0 + ct * 16 + l15) * 512 + k0 + lg * 8);
      acc[ct] = __builtin_amdgcn_mfma_f32_16x16x32_bf16(av, b, acc[ct], 0, 0, 0);
    }
  }
  // ---- svec: s[row] = sum_col acc*a_slice, reduce over 16 l15 lanes ----
  float aS[4], aD[4];
#pragma unroll
  for (int ct = 0; ct < 4; ++ct) {
    aS[ct] = a[ct * 16 + l15];
    aD[ct] = a[64 + ct * 16 + l15];
  }
#pragma unroll
  for (int r = 0; r < 4; ++r) {
    float s1 = acc[0][r] * aS[0] + acc[1][r] * aS[1] + acc[2][r] * aS[2] + acc[3][r] * aS[3];
    float s2 = acc[0][r] * aD[0] + acc[1][r] * aD[1] + acc[2][r] * aD[2] + acc[3][r] * aD[3];
#pragma unroll
    for (int off = 1; off < 16; off <<= 1) {
      s1 += __shfl_xor(s1, off);
      s2 += __shfl_xor(s2, off);
    }
    if (l15 == 0) {
      const int row = m0 + wv * 16 + lg * 4 + r;
      ssrcT[h * 4096 + row] = s1 * LOG2E;
      sdstT[h * 4096 + row] = s2 * LOG2E;
    }
  }
  // ---- transposed bf16 store: WhT[n0+c][m0+m] ----
#pragma unroll
  for (int ct = 0; ct < 4; ++ct)
#pragma unroll
    for (int r = 0; r < 4; ++r)
      tl[(ct * 16 + l15) * 65 + wv * 16 + lg * 4 + r] = acc[ct][r];
  __syncthreads();
  const int c = threadIdx.x >> 2, mb = (threadIdx.x & 3) * 16;
  s16x8 o0, o1;
#pragma unroll
  for (int k = 0; k < 8; ++k) o0[k] = bf16b(tl[c * 65 + mb + k]);
#pragma unroll
  for (int k = 0; k < 8; ++k) o1[k] = bf16b(tl[c * 65 + mb + 8 + k]);
  *(s16x8*)(WhT + (size_t)(n0 + c) * 4096 + m0 + mb) = o0;
  *(s16x8*)(WhT + (size_t)(n0 + c) * 4096 + m0 + mb + 8) = o1;
}

// grid (128 i-blocks, 8 j-slices) = 1024 blocks, 512 thr = 8 waves = 8 heads.
// Wave: 32 rows x its head's 64 cols x 512 j. Single-buffer; TLP hides latency.
__global__ __launch_bounds__(512, 4) void k_attn(
    const uint32_t* __restrict__ mask32,
    const ushort* __restrict__ WhT,
    const float* __restrict__ ssrcT,
    const float* __restrict__ sdstT,
    ushort* __restrict__ num,     // [8][4096][512] bf16
    float* __restrict__ lbuf) {   // [8][8][4096]
  const int lane = threadIdx.x & 63;
  const int h = threadIdx.x >> 6;  // wave == head
  const int l15 = lane & 15, lg = lane >> 4;
  const int i0 = blockIdx.x * 32;
  const int jh = blockIdx.y;
  const int jbase = jh * 512;

  const float sd0 = sdstT[h * 4096 + i0 + l15];
  const float sd1 = sdstT[h * 4096 + i0 + 16 + l15];
  const float* ssp = ssrcT + h * 4096 + jbase + lg * 8;
  const ushort* bp = WhT + (size_t)(h * 64 + l15) * 4096 + jbase + lg * 8;
  const uint32_t* mp0 = mask32 + (size_t)(i0 + l15) * 128 + (jbase >> 5);
  const uint32_t* mp1 = mask32 + (size_t)(i0 + 16 + l15) * 128 + (jbase >> 5);

  f32x4 acc[2][4] = {};
  float lacc0 = 0.f, lacc1 = 0.f;

  for (int jb = 0; jb < 512; jb += 32) {
    const float4 u = *(const float4*)(ssp + jb);
    const float4 v = *(const float4*)(ssp + jb + 4);
    const uint32_t mm0 = mp0[jb >> 5] >> (lg * 8);
    const uint32_t mm1 = mp1[jb >> 5] >> (lg * 8);
    const s16x8 b0 = *(const s16x8*)(bp + jb);
    const s16x8 b1 = *(const s16x8*)(bp + jb + 16 * 4096);
    const s16x8 b2 = *(const s16x8*)(bp + jb + 32 * 4096);
    const s16x8 b3 = *(const s16x8*)(bp + jb + 48 * 4096);
    const float s8[8] = {u.x, u.y, u.z, u.w, v.x, v.y, v.z, v.w};
    s16x8 pa0, pa1;
#pragma unroll
    for (int q = 0; q < 8; ++q) {
      float e0 = sd0 + s8[q]; e0 = fmaxf(e0, 0.2f * e0);
      float x0 = __builtin_amdgcn_exp2f(e0);
      float w0 = ((mm0 >> q) & 1) ? x0 : 0.f;
      lacc0 += w0; pa0[q] = bf16b(w0);
      float e1 = sd1 + s8[q]; e1 = fmaxf(e1, 0.2f * e1);
      float x1 = __builtin_amdgcn_exp2f(e1);
      float w1 = ((mm1 >> q) & 1) ? x1 : 0.f;
      lacc1 += w1; pa1[q] = bf16b(w1);
    }
    acc[0][0] = __builtin_amdgcn_mfma_f32_16x16x32_bf16(pa0, b0, acc[0][0], 0, 0, 0);
    acc[1][0] = __builtin_amdgcn_mfma_f32_16x16x32_bf16(pa1, b0, acc[1][0], 0, 0, 0);
    acc[0][1] = __builtin_amdgcn_mfma_f32_16x16x32_bf16(pa0, b1, acc[0][1], 0, 0, 0);
    acc[1][1] = __builtin_amdgcn_mfma_f32_16x16x32_bf16(pa1, b1, acc[1][1], 0, 0, 0);
    acc[0][2] = __builtin_amdgcn_mfma_f32_16x16x32_bf16(pa0, b2, acc[0][2], 0, 0, 0);
    acc[1][2] = __builtin_amdgcn_mfma_f32_16x16x32_bf16(pa1, b2, acc[1][2], 0, 0, 0);
    acc[0][3] = __builtin_amdgcn_mfma_f32_16x16x32_bf16(pa0, b3, acc[0][3], 0, 0, 0);
    acc[1][3] = __builtin_amdgcn_mfma_f32_16x16x32_bf16(pa1, b3, acc[1][3], 0, 0, 0);
  }

  lacc0 += __shfl_xor(lacc0, 16); lacc0 += __shfl_xor(lacc0, 32);
  lacc1 += __shfl_xor(lacc1, 16); lacc1 += __shfl_xor(lacc1, 32);
  if (lane < 16) {
    lbuf[((size_t)jh * 8 + h) * 4096 + i0 + lane] = lacc0;
    lbuf[((size_t)jh * 8 + h) * 4096 + i0 + 16 + lane] = lacc1;
  }
  ushort* np = num + (size_t)jh * 4096 * 512;
#pragma unroll
  for (int rt = 0; rt < 2; ++rt)
#pragma unroll
    for (int ct = 0; ct < 4; ++ct)
#pragma unroll
      for (int r = 0; r < 4; ++r)
        np[(size_t)(i0 + rt * 16 + lg * 4 + r) * 512 + h * 64 + ct * 16 + l15] =
            (ushort)bf16b(acc[rt][ct][r]);
}

// 256 blocks x 512 thr; block = 16 rows, thread = 1 col. linv shared via LDS.
__global__ __launch_bounds__(512) void k_stats(const ushort* __restrict__ num,
                                               const float* __restrict__ lbuf,
                                               float* __restrict__ linv,
                                               float* __restrict__ stats) {
  __shared__ float linv_s[128];
  const int t = threadIdx.x;
  const int r0 = blockIdx.x * 16;
  if (t < 128) {
    const int r = r0 + (t >> 3), hh = t & 7;
    float l = 0.f;
#pragma unroll
    for (int s = 0; s < 8; ++s) l += lbuf[((size_t)s * 8 + hh) * 4096 + r];
    const float inv = 1.0f / l;
    linv_s[t] = inv;
    linv[r * 8 + hh] = inv;
  }
  __syncthreads();
  const int c = t;
  const int hh = c >> 6;
  float s1 = 0.f, s2 = 0.f;
  for (int rr = 0; rr < 16; ++rr) {
    const int r = r0 + rr;
    float nsum = 0.f;
#pragma unroll
    for (int s = 0; s < 8; ++s)
      nsum += bf2f(num[(size_t)s * 4096 * 512 + (size_t)r * 512 + c]);
    const float v = nsum * linv_s[rr * 8 + hh];
    s1 += v; s2 += v * v;
  }
  atomicAdd(&stats[c], s1);
  atomicAdd(&stats[512 + c], s2);
}

// 1024 blocks x 256 thr; thread = 8 consecutive cols of one row.
__global__ __launch_bounds__(256) void k_apply(const ushort* __restrict__ num,
                                               const float* __restrict__ linv,
                                               const float* __restrict__ stats,
                                               const float* __restrict__ gamma,
                                               const float* __restrict__ beta,
                                               float* __restrict__ out) {
  const size_t idx8 = ((size_t)blockIdx.x * 256 + threadIdx.x) * 8;
  const int r = (int)(idx8 >> 9);
  const int c0 = (int)(idx8 & 511);
  const float li = linv[r * 8 + (c0 >> 6)];
  float nsum[8] = {};
#pragma unroll
  for (int s = 0; s < 8; ++s) {
    s16x8 nv = *(const s16x8*)(num + (size_t)s * 4096 * 512 + idx8);
#pragma unroll
    for (int k = 0; k < 8; ++k) nsum[k] += bf2f((ushort)nv[k]);
  }
#pragma unroll
  for (int k = 0; k < 8; ++k) {
    const int cc = c0 + k;
    const float mean = stats[cc] * (1.f / 4096.f);
    const float var = stats[512 + cc] * (1.f / 4096.f) - mean * mean;
    const float v = nsum[k] * li;
    const float val = (v - mean) * rsqrtf(var + 1e-5f) * gamma[cc] + beta[cc];
    out[idx8 + k] = fmaxf(val, 0.f);
  }
}

extern "C" void kernel_launch(void* const* d_in, const int* in_sizes, int n_in,
                              void* d_out, int out_size, void* d_ws, size_t ws_size,
                              hipStream_t stream) {
  const float* x = (const float*)d_in[0];
  const int* adj = (const int*)d_in[1];
  const float* W = (const float*)d_in[2];
  const float* a = (const float*)d_in[3];
  const float* gamma = (const float*)d_in[4];
  const float* beta = (const float*)d_in[5];
  float* out = (float*)d_out;

  char* ws = (char*)d_ws;
  size_t off = 0;
  auto alloc = [&](size_t bytes) -> void* {
    void* p = ws + off;
    off += (bytes + 255) & ~(size_t)255;
    return p;
  };
  // persistent region (~7.7 MB)
  ushort* WhT   = (ushort*)alloc((size_t)512 * 4096 * 2);
  float*  ssrcT = (float*)alloc((size_t)8 * 4096 * 4);
  float*  sdstT = (float*)alloc((size_t)8 * 4096 * 4);
  unsigned long long* maskw = (unsigned long long*)alloc((size_t)4096 * 64 * 8);
  float*  lbuf  = (float*)alloc((size_t)64 * 4096 * 4);
  float*  linv  = (float*)alloc((size_t)4096 * 8 * 4);
  float*  stats = (float*)alloc((size_t)1024 * 4);
  // overlay region: xb+wb (gemm inputs) aliased by num (attn output)
  const size_t ov = off;
  ushort* xb = (ushort*)(ws + ov);
  ushort* wb = (ushort*)(ws + ov + (size_t)4096 * 512 * 2);
  ushort* num = (ushort*)(ws + ov);           // [8][4096][512] bf16 = 33.5 MB
  // total ~41.2 MB

  hipLaunchKernelGGL(k_convert, dim3(2304), dim3(256), 0, stream, x, W, xb, wb);
  hipLaunchKernelGGL(k_pack, dim3(2048), dim3(256), 0, stream, adj, maskw, stats);
  hipLaunchKernelGGL(k_gemm, dim3(64, 8), dim3(256), 0, stream, xb, wb, a, WhT, ssrcT, sdstT);
  hipLaunchKernelGGL(k_attn, dim3(128, 8), dim3(512), 0, stream,
                     (const uint32_t*)maskw, WhT, ssrcT, sdstT, num, lbuf);
  hipLaunchKernelGGL(k_stats, dim3(256), dim3(512), 0, stream, num, lbuf, linv, stats);
  hipLaunchKernelGGL(k_apply, dim3(1024), dim3(256), 0, stream, num, linv, stats, gamma, beta, out);
}